// Round 7
// baseline (448.598 us; speedup 1.0000x reference)
//
#include <hip/hip_runtime.h>
#include <math.h>
#include <stdint.h>

#define NTOK   16384
#define DIM    4096
#define NEXP   256
#define TOPKG  4
#define TOPK   8
#define NSPLIT 4
#define KCHUNK (DIM / NSPLIT)   // 1024
#define BM     128
#define BK     32
#define NSTEPS (KCHUNK / BK)    // 32

typedef float v4f   __attribute__((ext_vector_type(4)));
typedef short short8 __attribute__((ext_vector_type(8)));

__device__ inline unsigned short f2bf(float x) {           // round-to-nearest-even
    unsigned u = __float_as_uint(x);
    return (unsigned short)((u + 0x7fffu + ((u >> 16) & 1u)) >> 16);
}
__device__ inline float bf2f(unsigned short h) {
    return __uint_as_float(((unsigned)h) << 16);
}
// 4-slot XOR swizzle within a 64B row (involution; verified R2: conflicts=0)
__device__ inline int swz4(int row, int slot) { return slot ^ ((row >> 1) & 3); }

// ---- W fp32 -> bf16 (hi, lo) row-major [256][4096], done once per call ----
__global__ __launch_bounds__(256) void wprep(const float* __restrict__ W,
                                             unsigned short* __restrict__ Wh,
                                             unsigned short* __restrict__ Wl) {
    int i = (blockIdx.x * 256 + threadIdx.x) * 4;
    float4 v = *(const float4*)(W + i);
    ushort4 h, l;
    h.x = f2bf(v.x); l.x = f2bf(v.x - bf2f(h.x));
    h.y = f2bf(v.y); l.y = f2bf(v.y - bf2f(h.y));
    h.z = f2bf(v.z); l.z = f2bf(v.z - bf2f(h.z));
    h.w = f2bf(v.w); l.w = f2bf(v.w - bf2f(h.w));
    *(ushort4*)(Wh + i) = h;
    *(ushort4*)(Wl + i) = l;
}

// ---- GEMM: P[z][t][e] = sum_{k in chunk z} X[t,k] W[e,k], bf16x2 3-pass MFMA ----
// B-direct structure: W is 4 MB = L2-resident, so B fragments load straight
// from global into registers (per-lane 16B of a 64B expert-row segment), reg-
// double-buffered across steps; the compiler's dataflow vmcnt covers them.
// LDS carries ONLY A (32 KB dbuf) -> 2 independent blocks/CU, 2 barriers/step,
// no vmcnt drain at barriers (in-flight loads target registers).
__global__ __launch_bounds__(256, 2) void gate_gemm(const float* __restrict__ X,
                                                    const unsigned short* __restrict__ Wh,
                                                    const unsigned short* __restrict__ Wl,
                                                    float* __restrict__ P) {
    __shared__ __align__(16) unsigned short Ah[2][BM * BK];    // 2 x 8 KB
    __shared__ __align__(16) unsigned short Al[2][BM * BK];    // -> 32 KB total

    const int t  = threadIdx.x;            // 0..255
    const int bm = blockIdx.x * BM;
    const int z  = blockIdx.y;
    const int k0 = z * KCHUNK;

    const int l  = t & 63;
    const int wc = t >> 6;                 // 0..3: 64-expert column slice
    const int lm = l & 15;
    const int lq = l >> 4;                 // 16B k-slot (0..3)

    // A staging: thread t -> row t>>1 (0..127), k-half (t&1)*16
    const int ar = t >> 1;
    const float* xrow = X + (size_t)(bm + ar) * DIM + k0 + (t & 1) * 16;

    // per-lane B sources (L2-resident): expert e = wc*64 + c*16 + lm
    const unsigned short* bsrc_h[4];
    const unsigned short* bsrc_l[4];
#pragma unroll
    for (int c = 0; c < 4; ++c) {
        int e = wc * 64 + c * 16 + lm;
        bsrc_h[c] = Wh + (size_t)e * DIM + k0 + lq * 8;
        bsrc_l[c] = Wl + (size_t)e * DIM + k0 + lq * 8;
    }

#define ACONV(buf, v0, v1, v2, v3)                                                  \
    do {                                                                            \
        float4 xa_[4] = {v0, v1, v2, v3};                                           \
        _Pragma("unroll")                                                           \
        for (int i_ = 0; i_ < 4; ++i_) {                                            \
            ushort4 h_, lo_;                                                        \
            h_.x = f2bf(xa_[i_].x); lo_.x = f2bf(xa_[i_].x - bf2f(h_.x));           \
            h_.y = f2bf(xa_[i_].y); lo_.y = f2bf(xa_[i_].y - bf2f(h_.y));           \
            h_.z = f2bf(xa_[i_].z); lo_.z = f2bf(xa_[i_].z - bf2f(h_.z));           \
            h_.w = f2bf(xa_[i_].w); lo_.w = f2bf(xa_[i_].w - bf2f(h_.w));           \
            int j_ = (t & 1) * 4 + i_;                                              \
            int idx_ = ar * BK + swz4(ar, j_ >> 1) * 8 + (j_ & 1) * 4;              \
            *(ushort4*)&Ah[buf][idx_] = h_;                                         \
            *(ushort4*)&Al[buf][idx_] = lo_;                                        \
        }                                                                           \
    } while (0)

#define LOADB(dsth, dstl, step)                                                     \
    do {                                                                            \
        _Pragma("unroll")                                                           \
        for (int c_ = 0; c_ < 4; ++c_) {                                            \
            dsth[c_] = *(const short8*)(bsrc_h[c_] + (step) * BK);                  \
            dstl[c_] = *(const short8*)(bsrc_l[c_] + (step) * BK);                  \
        }                                                                           \
    } while (0)

    v4f acc[8][4] = {};
    short8 bAh[4], bAl[4], bBh[4], bBl[4];   // B reg double-buffer (static idx)
    float4 xv0, xv1, xv2, xv3;

    // ---- prologue: A(0)+B(0) loads, A(0) -> LDS buf 0 ----
    {
        float4 p0 = *(const float4*)(xrow);
        float4 p1 = *(const float4*)(xrow + 4);
        float4 p2 = *(const float4*)(xrow + 8);
        float4 p3 = *(const float4*)(xrow + 12);
        LOADB(bAh, bAl, 0);
        ACONV(0, p0, p1, p2, p3);            // compiler waits the xv regs only
        asm volatile("s_waitcnt lgkmcnt(0)" ::: "memory");
        __builtin_amdgcn_s_barrier();
    }

    int cur = 0;
#define STEP(s, bch, bcl, bnh, bnl)                                                 \
    do {                                                                            \
        const bool pf_ = ((s) + 1 < NSTEPS);                                        \
        if (pf_) {                                                                  \
            const float* xn_ = xrow + ((s) + 1) * BK;                               \
            xv0 = *(const float4*)(xn_);                                            \
            xv1 = *(const float4*)(xn_ + 4);                                        \
            xv2 = *(const float4*)(xn_ + 8);                                        \
            xv3 = *(const float4*)(xn_ + 12);                                       \
            LOADB(bnh, bnl, (s) + 1);                                               \
        }                                                                           \
        __builtin_amdgcn_s_setprio(1);                                              \
        _Pragma("unroll")                                                           \
        for (int r_ = 0; r_ < 8; ++r_) {                                            \
            const int m_ = r_ * 16 + lm;                                            \
            short8 ah_ = *(const short8*)&Ah[cur][m_ * BK + swz4(m_, lq) * 8];      \
            short8 al_ = *(const short8*)&Al[cur][m_ * BK + swz4(m_, lq) * 8];      \
            _Pragma("unroll")                                                       \
            for (int c_ = 0; c_ < 4; ++c_) {                                        \
                acc[r_][c_] = __builtin_amdgcn_mfma_f32_16x16x32_bf16(ah_, bch[c_], acc[r_][c_], 0, 0, 0); \
                acc[r_][c_] = __builtin_amdgcn_mfma_f32_16x16x32_bf16(ah_, bcl[c_], acc[r_][c_], 0, 0, 0); \
                acc[r_][c_] = __builtin_amdgcn_mfma_f32_16x16x32_bf16(al_, bch[c_], acc[r_][c_], 0, 0, 0); \
            }                                                                       \
        }                                                                           \
        __builtin_amdgcn_s_setprio(0);                                              \
        if (pf_) ACONV(cur ^ 1, xv0, xv1, xv2, xv3);                                \
        asm volatile("s_waitcnt lgkmcnt(0)" ::: "memory");                          \
        __builtin_amdgcn_s_barrier();                                               \
        cur ^= 1;                                                                   \
    } while (0)

#pragma unroll 1
    for (int s2 = 0; s2 < NSTEPS; s2 += 2) {
        STEP(s2,     bAh, bAl, bBh, bBl);    // consume B(s2), prefetch B(s2+1)
        STEP(s2 + 1, bBh, bBl, bAh, bAl);    // consume B(s2+1), prefetch B(s2+2)
    }
#undef STEP
#undef LOADB
#undef ACONV

    // epilogue: C/D layout col=lane&15, row=lq*4+reg (verified m89/m91)
    float* Pb = P + ((size_t)z * NTOK + bm) * NEXP;
#pragma unroll
    for (int r = 0; r < 8; ++r)
#pragma unroll
        for (int c = 0; c < 4; ++c)
#pragma unroll
            for (int g = 0; g < 4; ++g)
                Pb[(size_t)(r * 16 + lq * 4 + g) * NEXP + wc * 64 + c * 16 + lm] = acc[r][c][g];
}

// ---- fused reduce (4 partials, fixed order) + routing: one wave per token ----
__global__ __launch_bounds__(256) void gate_route(const float* __restrict__ P,
                                                  float* __restrict__ outw,
                                                  float* __restrict__ outi) {
    const int lane = threadIdx.x & 63;
    const int tok  = (blockIdx.x * blockDim.x + threadIdx.x) >> 6;
    if (tok >= NTOK) return;

    float l[4] = {0.f, 0.f, 0.f, 0.f};
#pragma unroll
    for (int z = 0; z < NSPLIT; ++z) {   // fixed order: deterministic across runs
        float4 v = *(const float4*)(P + ((size_t)z * NTOK + tok) * NEXP + lane * 4);
        l[0] += v.x; l[1] += v.y; l[2] += v.z; l[3] += v.w;
    }

    float lmax = fmaxf(fmaxf(l[0], l[1]), fmaxf(l[2], l[3]));
    float m = lmax;
#pragma unroll
    for (int o = 32; o; o >>= 1) m = fmaxf(m, __shfl_xor(m, o));

    float s = __expf(l[0] - m) + __expf(l[1] - m) + __expf(l[2] - m) + __expf(l[3] - m);
#pragma unroll
    for (int o = 32; o; o >>= 1) s += __shfl_xor(s, o);

    float gm = lmax;
#pragma unroll
    for (int o = 4; o; o >>= 1) gm = fmaxf(gm, __shfl_xor(gm, o));

    const int g = lane >> 3;
    int rank = 0;
#pragma unroll
    for (int gg = 0; gg < 8; ++gg) {
        float vg = __shfl(gm, gg * 8);
        rank += (vg > gm) || (vg == gm && gg < g);
    }
    const bool allowed = rank < TOPKG;

    float mv[4];
#pragma unroll
    for (int j = 0; j < 4; ++j) mv[j] = allowed ? l[j] : -INFINITY;

    float wsel = 0.0f;
    int   isel = 0;

    for (int k = 0; k < TOPK; ++k) {
        float bv = mv[0];
        int   bi = lane * 4;
        if (mv[1] > bv) { bv = mv[1]; bi = lane * 4 + 1; }
        if (mv[2] > bv) { bv = mv[2]; bi = lane * 4 + 2; }
        if (mv[3] > bv) { bv = mv[3]; bi = lane * 4 + 3; }
#pragma unroll
        for (int o = 32; o; o >>= 1) {
            float ov = __shfl_xor(bv, o);
            int   oi = __shfl_xor(bi, o);
            if (ov > bv || (ov == bv && oi < bi)) { bv = ov; bi = oi; }
        }
        if (lane == k) { wsel = __expf(bv - m) / s; isel = bi; }
        if ((bi >> 2) == lane) mv[bi & 3] = -INFINITY;
    }

    if (lane < TOPK) {
        outw[(size_t)tok * TOPK + lane] = wsel;
        outi[(size_t)tok * TOPK + lane] = (float)isel;
    }
}

extern "C" void kernel_launch(void* const* d_in, const int* in_sizes, int n_in,
                              void* d_out, int out_size, void* d_ws, size_t ws_size,
                              hipStream_t stream) {
    const float* x  = (const float*)d_in[0];   // [16384, 4096]
    const float* wt = (const float*)d_in[1];   // [256, 4096]

    // ws layout: partials [4][16384][256] f32 (64 MB) | Wh (2 MB) | Wl (2 MB)
    float* P = (float*)d_ws;
    unsigned short* Wh = (unsigned short*)((char*)d_ws + (size_t)NSPLIT * NTOK * NEXP * 4);
    unsigned short* Wl = Wh + (size_t)NEXP * DIM;

    float* outw = (float*)d_out;
    float* outi = (float*)d_out + (size_t)NTOK * TOPK;

    wprep<<<(NEXP * DIM) / (256 * 4), 256, 0, stream>>>(wt, Wh, Wl);

    dim3 ggrid(NTOK / BM, NSPLIT);   // (128, 4) = 512 blocks, 2/CU, destaggered
    gate_gemm<<<ggrid, 256, 0, stream>>>(x, Wh, Wl, P);

    gate_route<<<(NTOK * 64) / 256, 256, 0, stream>>>(P, outw, outi);
}